// Round 3
// baseline (306.346 us; speedup 1.0000x reference)
//
#include <hip/hip_runtime.h>

// DeformConvBlock B=4,C=64,H=W=256,OUT=64 — fp16 MFMA pipeline.
// R9: two attacks.
//  K1: the total-minus-deform gap (~100us) never moved across 3 K1 variants;
//      K1's reads were 256B/instr at exact 256KB pow2 stride (channel-plane
//      hops) -> small segments + stride aliasing. Now thread=(4px,16ch):
//      float4 reads = 1KB contiguous per wave instr; each thread writes its
//      4 consecutive granules (64B contiguous).
//  K2: still latency-bound (Mfma 8.8%, VALU 24%, occ 35%; VGPR 64 likely
//      excl. 48 AGPR -> ~112 regs -> 16 waves/CU). Wave tile 32px -> 16px:
//      acc 32->16 AGPR, acc1 16->8, corner live-set halved -> ~80 regs ->
//      ~20-24 waves/CU; grid 2048->4096 blocks. Per-px VALU/MFMA unchanged.

typedef _Float16 half8 __attribute__((ext_vector_type(8)));
typedef _Float16 h2    __attribute__((ext_vector_type(2)));
typedef float floatx4  __attribute__((ext_vector_type(4)));

namespace {
constexpr int B_ = 4, C_ = 64, H_ = 256, W_ = 256, OUT_ = 64;
constexpr int HW_ = H_ * W_;
constexpr size_t XT_BYTES = (size_t)B_ * HW_ * C_ * 2;      // 32 MB plane-major f16
constexpr size_t WOFF_OFF = XT_BYTES;                        // [9][2][2][64][8] f16
constexpr int    WOFF_N   = 9 * 2 * 2 * 64 * 8;
constexpr size_t WDEF_OFF = WOFF_OFF + (size_t)WOFF_N * 2;   // [9][2][4][64][8] f16
constexpr int    WDEF_N   = 9 * 2 * 4 * 64 * 8;
// xt granule index: (((b*256 + y)*8 + kcq)*256 + px), each granule = 8 f16 = 16B
}

// ------- K1: x CHW f32 -> plane-major f16 (+ weight prep in first 32 blocks) -
// One block per (b,y) row. Thread = (4 px, 16 ch): reads are float4 -> each
// wave instr covers 64 lanes x 16B = 1KB contiguous of one channel row.
// Stores: per (kcq): thread's 4 granules are consecutive -> 64B contiguous.
__global__ __launch_bounds__(256)
void transpose_x(const float* __restrict__ x, _Float16* __restrict__ xt,
                 const float* __restrict__ w_off, const float* __restrict__ w_def,
                 _Float16* __restrict__ wof, _Float16* __restrict__ wdf)
{
    const int bid = blockIdx.x;            // b*256 + y
    const int b = bid >> 8, y = bid & 255;
    const int t64 = threadIdx.x & 63;
    const int ch0 = (threadIdx.x >> 6) * 16;     // wave w owns channels 16w..16w+15
    const int pxg = t64 * 4;
    const float* __restrict__ xp = x + (size_t)b * C_ * HW_ + y * W_ + pxg;

#pragma unroll
    for (int q = 0; q < 2; ++q) {
        float4 f[8];
#pragma unroll
        for (int cc = 0; cc < 8; ++cc)
            f[cc] = *(const float4*)&xp[(size_t)(ch0 + q * 8 + cc) * HW_];
        const int kcq = (ch0 >> 3) + q;
        _Float16* __restrict__ dg = xt + ((size_t)(bid * 8 + kcq) * 256 + pxg) * 8;
#pragma unroll
        for (int j = 0; j < 4; ++j) {
            union { _Float16 h[8]; uint4 u; } g;
#pragma unroll
            for (int cc = 0; cc < 8; ++cc)
                g.h[cc] = (_Float16)(((const float*)&f[cc])[j]);
            *(uint4*)(dg + j * 8) = g.u;
        }
    }

    // ---- weight prep (blocks 0..31): coalesced reads, scattered stores ----
    if (bid < 32) {
        const int i0 = bid * 256 + threadIdx.x;          // 0..8191
        for (int s = i0; s < OUT_ * C_ * 9; s += 8192) {  // wdf: 36864 elems
            const int n = s / 576;                        // 576 = 64*9
            const int r = s - n * 576;
            const int c = r / 9;
            const int tap = r - c * 9;
            const int idx = ((((tap * 2 + (c >> 5)) * 4 + (n >> 4)) * 64
                              + ((c >> 3) & 3) * 16 + (n & 15)) << 3) + (c & 7);
            wdf[idx] = (_Float16)w_def[s];
        }
        for (int s = i0; s < 18 * C_ * 9; s += 8192) {    // wof: 10368 elems
            const int n = s / 576;
            const int r = s - n * 576;
            const int c = r / 9;
            const int tap = r - c * 9;
            const int idx = ((((tap * 2 + (c >> 5)) * 2 + (n >> 4)) * 64
                              + ((c >> 3) & 3) * 16 + (n & 15)) << 3) + (c & 7);
            wof[idx] = (_Float16)w_off[s];
        }
        // zero padding slots (n = 16 + (lane&15) >= 18); disjoint from above
        for (int i = i0; i < WOFF_N; i += 8192) {
            const int lane = (i >> 3) & 63, nt = (i >> 9) & 1;
            if (nt == 1 && (lane & 15) >= 2) wof[i] = (_Float16)0.0f;
        }
    }
}

// ---------------- K2 helpers ----------------
// a[i] = granule base (yc*2048 + xc); add (kc*4+lq)*256 for the channel plane.
__device__ __forceinline__ void bilin_setup(float ys, float xs, int* a, float* w)
{
    const float y0f = floorf(ys), x0f = floorf(xs);
    const float ly = ys - y0f, lx = xs - x0f;
    const int y0 = (int)y0f, x0 = (int)x0f;
    const int y1 = y0 + 1, x1 = x0 + 1;
    const int y0c = min(max(y0, 0), H_ - 1);
    const int y1c = min(max(y1, 0), H_ - 1);
    const int x0c = min(max(x0, 0), W_ - 1);
    const int x1c = min(max(x1, 0), W_ - 1);
    const float fy0 = (y0 >= 0 && y0 < H_) ? 1.0f : 0.0f;
    const float fy1 = (y1 >= 0 && y1 < H_) ? 1.0f : 0.0f;
    const float fx0 = (x0 >= 0 && x0 < W_) ? 1.0f : 0.0f;
    const float fx1 = (x1 >= 0 && x1 < W_) ? 1.0f : 0.0f;
    a[0] = y0c * 2048 + x0c;  w[0] = (1.0f - ly) * (1.0f - lx) * fy0 * fx0;
    a[1] = y0c * 2048 + x1c;  w[1] = (1.0f - ly) * lx          * fy0 * fx1;
    a[2] = y1c * 2048 + x0c;  w[2] = ly          * (1.0f - lx) * fy1 * fx0;
    a[3] = y1c * 2048 + x1c;  w[3] = ly          * lx          * fy1 * fx1;
}

// ---------------- K2: fused deform conv (f16 MFMA), 16px per wave ----------
__global__ __launch_bounds__(256, 5)
void deform_main(const _Float16* __restrict__ xt,
                 const _Float16* __restrict__ wof,
                 const float* __restrict__ b_off,
                 const _Float16* __restrict__ wdf,
                 const float* __restrict__ b_def,
                 float* __restrict__ out)
{
    __shared__ float off_lds[64 * 18];        // per-pixel offsets (64 px window)

    const int tid = threadIdx.x;
    const int lane = tid & 63;
    const int wv = tid >> 6;            // wave id: px [wv*16, wv*16+16)
    const int lm = lane & 15;
    const int lq = lane >> 4;
    const int bid = blockIdx.x;                      // 4096
    const int uid = (bid & 7) * 512 + (bid >> 3);    // XCD band swizzle (bijective)
    const int col = uid & 3;
    const int y = (uid >> 2) & 255;
    const int b = uid >> 10;
    const int base = col * 64 + wv * 16;             // this wave's px window
    const _Float16* __restrict__ xtb = xt + (size_t)b * HW_ * C_;

    // ================= phase 1: offsets via MFMA =================
    {
        floatx4 acc1[2];
#pragma unroll
        for (int nt = 0; nt < 2; ++nt) acc1[nt] = (floatx4)0.0f;

#pragma unroll
        for (int tap = 0; tap < 9; ++tap) {
            const int dy = tap / 3 - 1, dx = tap % 3 - 1;
            const int ys = y + dy;
            const bool yok = (unsigned)ys < 256u;
            const int ysc = min(max(ys, 0), 255);
#pragma unroll
            for (int kc = 0; kc < 2; ++kc) {
                half8 bfr[2];
#pragma unroll
                for (int nt = 0; nt < 2; ++nt)
                    bfr[nt] = *(const half8*)(wof +
                        ((size_t)(((tap * 2 + kc) * 2 + nt) * 64 + lane)) * 8);
                const int plane = (kc * 4 + lq) * 256;
                const int px_s = base + lm + dx;
                const bool vld = yok && ((unsigned)px_s < 256u);
                const int pxc = min(max(px_s, 0), 255);
                uint4 t = *(const uint4*)(xtb +
                    ((size_t)(ysc * 2048 + plane + pxc)) * 8);
                if (!vld) { t.x = 0u; t.y = 0u; t.z = 0u; t.w = 0u; }
                const half8 afr = __builtin_bit_cast(half8, t);
#pragma unroll
                for (int nt = 0; nt < 2; ++nt)
                    acc1[nt] = __builtin_amdgcn_mfma_f32_16x16x32_f16(
                        afr, bfr[nt], acc1[nt], 0, 0, 0);
            }
        }
#pragma unroll
        for (int nt = 0; nt < 2; ++nt) {
            const int j = nt * 16 + lm;
            if (j < 18) {
                const float bj = b_off[j];
#pragma unroll
                for (int r = 0; r < 4; ++r) {
                    const int lpx = wv * 16 + lq * 4 + r;
                    off_lds[lpx * 18 + j] = acc1[nt][r] + bj;
                }
            }
        }
    }
    __syncthreads();   // the ONLY barrier

    // ================= phase 2: per-thread f16 A-frag gather + MFMA =========
    floatx4 acc[4];
#pragma unroll
    for (int ot = 0; ot < 4; ++ot) acc[ot] = (floatx4)0.0f;

#pragma unroll
    for (int tap = 0; tap < 9; ++tap) {
        const int ki = tap / 3, kj = tap % 3;
        const int lpx = wv * 16 + lm;
        const float2 o2 = *(const float2*)&off_lds[lpx * 18 + tap * 2];
        const float ys = (float)(y + ki - 1) + o2.x;
        const float xs = (float)(col * 64 + lpx + kj - 1) + o2.y;
        int ca[4];
        float cwf[4];
        bilin_setup(ys, xs, ca, cwf);
        h2 cw[4];
#pragma unroll
        for (int c = 0; c < 4; ++c) cw[c] = (h2)((_Float16)cwf[c]);

#pragma unroll
        for (int kc = 0; kc < 2; ++kc) {
            half8 bfr[4];
#pragma unroll
            for (int ot = 0; ot < 4; ++ot)
                bfr[ot] = *(const half8*)(wdf +
                    ((size_t)(((tap * 2 + kc) * 4 + ot) * 64 + lane)) * 8);

            const int plane = (kc * 4 + lq) * 256;
            union Uc { uint4 u; h2 p[4]; } c0, c1, c2, c3;
            c0.u = *(const uint4*)(xtb + (size_t)(ca[0] + plane) * 8);
            c1.u = *(const uint4*)(xtb + (size_t)(ca[1] + plane) * 8);
            c2.u = *(const uint4*)(xtb + (size_t)(ca[2] + plane) * 8);
            c3.u = *(const uint4*)(xtb + (size_t)(ca[3] + plane) * 8);
            union Rr { h2 s[4]; half8 v; } r;
#pragma unroll
            for (int k = 0; k < 4; ++k)
                r.s[k] = cw[0] * c0.p[k] + cw[1] * c1.p[k]
                       + cw[2] * c2.p[k] + cw[3] * c3.p[k];
#pragma unroll
            for (int ot = 0; ot < 4; ++ot)
                acc[ot] = __builtin_amdgcn_mfma_f32_16x16x32_f16(
                    r.v, bfr[ot], acc[ot], 0, 0, 0);
        }
    }

    // ================= epilogue: float4 stores =================
#pragma unroll
    for (int ot = 0; ot < 4; ++ot) {
        const int o = ot * 16 + lm;
        const float bd = b_def[o];
        const int pxs = base + lq * 4;
        const floatx4 a = acc[ot];
        float4 v = make_float4(a[0] + bd, a[1] + bd, a[2] + bd, a[3] + bd);
        *(float4*)&out[(((size_t)b * OUT_ + o) * H_ + y) * W_ + pxs] = v;
    }
}

extern "C" void kernel_launch(void* const* d_in, const int* in_sizes, int n_in,
                              void* d_out, int out_size, void* d_ws, size_t ws_size,
                              hipStream_t stream)
{
    const float* x     = (const float*)d_in[0];
    const float* w_off = (const float*)d_in[1];
    const float* b_off = (const float*)d_in[2];
    const float* w_def = (const float*)d_in[3];
    const float* b_def = (const float*)d_in[4];
    float* out = (float*)d_out;

    _Float16* xt  = (_Float16*)d_ws;
    _Float16* wof = (_Float16*)((char*)d_ws + WOFF_OFF);
    _Float16* wdf = (_Float16*)((char*)d_ws + WDEF_OFF);

    transpose_x<<<dim3(B_ * H_), dim3(256), 0, stream>>>(
        x, xt, w_off, w_def, wof, wdf);
    deform_main<<<dim3(B_ * H_ * 4), dim3(256), 0, stream>>>(
        xt, wof, b_off, wdf, b_def, out);
}

// Round 4
// 224.841 us; speedup vs baseline: 1.3625x; 1.3625x over previous
//
#include <hip/hip_runtime.h>

// DeformConvBlock B=4,C=64,H=W=256,OUT=64 — fp16 MFMA pipeline.
// R10: revert to R8 geometry (32px/wave, 4-row blocks, 2048 blocks; 130us
// measured) + MANUAL depth-1 software pipeline. R9 proved TLP isn't the
// limit (occ 68% was slower); R7 proved the compiler won't hoist gathers
// itself. So: explicit double-buffered staging regs — at group (tap,kc),
// the next group's 8 corner gathers are issued before the current group's
// blend+MFMA consumes its buffer; next tap's bilin_setup runs under the
// in-flight loads. Same in phase 1 (2-load groups). launch_bounds(256,3)
// (regs +~50; measured occupancy was ~11-12 waves anyway).

typedef _Float16 half8 __attribute__((ext_vector_type(8)));
typedef _Float16 h2    __attribute__((ext_vector_type(2)));
typedef float floatx4  __attribute__((ext_vector_type(4)));

namespace {
constexpr int B_ = 4, C_ = 64, H_ = 256, W_ = 256, OUT_ = 64;
constexpr int HW_ = H_ * W_;
constexpr size_t XT_BYTES = (size_t)B_ * HW_ * C_ * 2;      // 32 MB plane-major f16
constexpr size_t WOFF_OFF = XT_BYTES;                        // [9][2][2][64][8] f16
constexpr int    WOFF_N   = 9 * 2 * 2 * 64 * 8;
constexpr size_t WDEF_OFF = WOFF_OFF + (size_t)WOFF_N * 2;   // [9][2][4][64][8] f16
constexpr int    WDEF_N   = 9 * 2 * 4 * 64 * 8;
// xt granule index: (((b*256 + y)*8 + kcq)*256 + px), each granule = 8 f16 = 16B
}

// ------- K1: x CHW f32 -> plane-major f16 (+ weight prep in first 32 blocks) -
__global__ __launch_bounds__(256)
void transpose_x(const float* __restrict__ x, _Float16* __restrict__ xt,
                 const float* __restrict__ w_off, const float* __restrict__ w_def,
                 _Float16* __restrict__ wof, _Float16* __restrict__ wdf)
{
    const int bid = blockIdx.x;            // b*256 + y
    const int b = bid >> 8, y = bid & 255;
    const int px = threadIdx.x;
    const float* __restrict__ xp = x + (size_t)b * C_ * HW_ + y * W_ + px;

    union { _Float16 h[64]; uint4 u[8]; } v;
#pragma unroll
    for (int c = 0; c < C_; ++c) v.h[c] = (_Float16)xp[(size_t)c * HW_];

    // granule (bid*8 + k)*256 + px, elem offset x8 -> per store instr 1KB contig
    _Float16* __restrict__ d0 = xt + ((size_t)(bid * 8) * 256 + px) * 8;
#pragma unroll
    for (int k = 0; k < 8; ++k)
        *(uint4*)(d0 + (size_t)k * 256 * 8) = v.u[k];

    // ---- weight prep (blocks 0..31): coalesced reads, scattered stores ----
    if (bid < 32) {
        const int i0 = bid * 256 + threadIdx.x;          // 0..8191
        for (int s = i0; s < OUT_ * C_ * 9; s += 8192) {  // wdf: 36864 elems
            const int n = s / 576;                        // 576 = 64*9
            const int r = s - n * 576;
            const int c = r / 9;
            const int tap = r - c * 9;
            const int idx = ((((tap * 2 + (c >> 5)) * 4 + (n >> 4)) * 64
                              + ((c >> 3) & 3) * 16 + (n & 15)) << 3) + (c & 7);
            wdf[idx] = (_Float16)w_def[s];
        }
        for (int s = i0; s < 18 * C_ * 9; s += 8192) {    // wof: 10368 elems
            const int n = s / 576;
            const int r = s - n * 576;
            const int c = r / 9;
            const int tap = r - c * 9;
            const int idx = ((((tap * 2 + (c >> 5)) * 2 + (n >> 4)) * 64
                              + ((c >> 3) & 3) * 16 + (n & 15)) << 3) + (c & 7);
            wof[idx] = (_Float16)w_off[s];
        }
        // zero padding slots (n = 16 + (lane&15) >= 18); disjoint from above
        for (int i = i0; i < WOFF_N; i += 8192) {
            const int lane = (i >> 3) & 63, nt = (i >> 9) & 1;
            if (nt == 1 && (lane & 15) >= 2) wof[i] = (_Float16)0.0f;
        }
    }
}

// ---------------- K2 helpers ----------------
// a[i] = granule base (yc*2048 + xc); add (kc*4+lq)*256 for the channel plane.
__device__ __forceinline__ void bilin_setup(float ys, float xs, int* a, float* w)
{
    const float y0f = floorf(ys), x0f = floorf(xs);
    const float ly = ys - y0f, lx = xs - x0f;
    const int y0 = (int)y0f, x0 = (int)x0f;
    const int y1 = y0 + 1, x1 = x0 + 1;
    const int y0c = min(max(y0, 0), H_ - 1);
    const int y1c = min(max(y1, 0), H_ - 1);
    const int x0c = min(max(x0, 0), W_ - 1);
    const int x1c = min(max(x1, 0), W_ - 1);
    const float fy0 = (y0 >= 0 && y0 < H_) ? 1.0f : 0.0f;
    const float fy1 = (y1 >= 0 && y1 < H_) ? 1.0f : 0.0f;
    const float fx0 = (x0 >= 0 && x0 < W_) ? 1.0f : 0.0f;
    const float fx1 = (x1 >= 0 && x1 < W_) ? 1.0f : 0.0f;
    a[0] = y0c * 2048 + x0c;  w[0] = (1.0f - ly) * (1.0f - lx) * fy0 * fx0;
    a[1] = y0c * 2048 + x1c;  w[1] = (1.0f - ly) * lx          * fy0 * fx1;
    a[2] = y1c * 2048 + x0c;  w[2] = ly          * (1.0f - lx) * fy1 * fx0;
    a[3] = y1c * 2048 + x1c;  w[3] = ly          * lx          * fy1 * fx1;
}

// ---------------- K2: fused deform conv (f16 MFMA), pipelined ----------------
__global__ __launch_bounds__(256, 3)
void deform_main(const _Float16* __restrict__ xt,
                 const _Float16* __restrict__ wof,
                 const float* __restrict__ b_off,
                 const _Float16* __restrict__ wdf,
                 const float* __restrict__ b_def,
                 float* __restrict__ out)
{
    __shared__ float off_lds[128 * 18];       // per-pixel offsets (4 rows x 32 px)

    const int tid = threadIdx.x;
    const int lane = tid & 63;
    const int wv = tid >> 6;            // wave id: row y0+wv
    const int lm = lane & 15;
    const int lq = lane >> 4;
    const int bid = blockIdx.x;                      // 2048
    const int uid = (bid & 7) * 256 + (bid >> 3);    // XCD band swizzle
    const int colc = uid & 7;
    const int rowg = (uid >> 3) & 63;
    const int b = uid >> 9;
    const int y0 = rowg * 4;
    const int y = y0 + wv;                           // this wave's row
    const int base = colc * 32;                      // px window [base, base+32)
    const _Float16* __restrict__ xtb = xt + (size_t)b * HW_ * C_;

    // ================= phase 1: offsets via MFMA (depth-1 pipelined) ========
    {
        floatx4 acc1[2][2];
#pragma unroll
        for (int pt = 0; pt < 2; ++pt)
#pragma unroll
            for (int nt = 0; nt < 2; ++nt) acc1[pt][nt] = (floatx4)0.0f;

        uint4 st1[2][2];     // [group parity][pt]
        bool  v1[2][2];

#define P1_ISSUE(TAP, KC, PAR) do {                                          \
        const int dy_ = (TAP) / 3 - 1, dx_ = (TAP) % 3 - 1;                  \
        const int ys_ = y + dy_;                                             \
        const bool yok_ = (unsigned)ys_ < 256u;                              \
        const int ysc_ = min(max(ys_, 0), 255);                              \
        _Pragma("unroll")                                                    \
        for (int pt_ = 0; pt_ < 2; ++pt_) {                                  \
            const int pxs_ = base + pt_ * 16 + lm + dx_;                     \
            v1[PAR][pt_] = yok_ && ((unsigned)pxs_ < 256u);                  \
            const int pxc_ = min(max(pxs_, 0), 255);                         \
            st1[PAR][pt_] = *(const uint4*)(xtb +                            \
                (size_t)(ysc_ * 2048 + ((KC) * 4 + lq) * 256 + pxc_) * 8);   \
        } } while (0)

        P1_ISSUE(0, 0, 0);
#pragma unroll
        for (int g = 0; g < 18; ++g) {
            const int tap = g >> 1, kc = g & 1, par = g & 1;
            if (g < 17) { P1_ISSUE((g + 1) >> 1, (g + 1) & 1, (g + 1) & 1); }
            half8 bfr[2];
#pragma unroll
            for (int nt = 0; nt < 2; ++nt)
                bfr[nt] = *(const half8*)(wof +
                    ((size_t)(((tap * 2 + kc) * 2 + nt) * 64 + lane)) * 8);
#pragma unroll
            for (int pt = 0; pt < 2; ++pt) {
                uint4 t = st1[par][pt];
                if (!v1[par][pt]) { t.x = 0u; t.y = 0u; t.z = 0u; t.w = 0u; }
                const half8 afr = __builtin_bit_cast(half8, t);
#pragma unroll
                for (int nt = 0; nt < 2; ++nt)
                    acc1[pt][nt] = __builtin_amdgcn_mfma_f32_16x16x32_f16(
                        afr, bfr[nt], acc1[pt][nt], 0, 0, 0);
            }
        }
#undef P1_ISSUE

#pragma unroll
        for (int nt = 0; nt < 2; ++nt) {
            const int j = nt * 16 + lm;
            if (j < 18) {
                const float bj = b_off[j];
#pragma unroll
                for (int pt = 0; pt < 2; ++pt) {
#pragma unroll
                    for (int r = 0; r < 4; ++r) {
                        const int lpx = wv * 32 + pt * 16 + lq * 4 + r;
                        off_lds[lpx * 18 + j] = acc1[pt][nt][r] + bj;
                    }
                }
            }
        }
    }
    __syncthreads();   // the ONLY barrier

    // ================= phase 2: pipelined gather + MFMA =====================
    floatx4 acc[2][4];
#pragma unroll
    for (int pt = 0; pt < 2; ++pt)
#pragma unroll
        for (int ot = 0; ot < 4; ++ot) acc[pt][ot] = (floatx4)0.0f;

    int   ca2[2][2][4];   // [tap parity][pt][corner] granule bases
    h2    cw2[2][2][4];   // [tap parity][pt][corner] f16 blend weights
    uint4 stc[2][2][4];   // [group parity][pt][corner] staged corner data

#define P2_BILIN(TAP, TP) do {                                               \
        const int ki_ = (TAP) / 3, kj_ = (TAP) % 3;                          \
        _Pragma("unroll")                                                    \
        for (int pt_ = 0; pt_ < 2; ++pt_) {                                  \
            const int lpx_ = wv * 32 + pt_ * 16 + lm;                        \
            const float2 o2_ = *(const float2*)&off_lds[lpx_ * 18 + (TAP) * 2]; \
            const float ys_ = (float)(y + ki_ - 1) + o2_.x;                  \
            const float xs_ = (float)(base + pt_ * 16 + lm + kj_ - 1) + o2_.y; \
            float cwf_[4];                                                   \
            bilin_setup(ys_, xs_, ca2[TP][pt_], cwf_);                       \
            _Pragma("unroll")                                                \
            for (int c_ = 0; c_ < 4; ++c_)                                   \
                cw2[TP][pt_][c_] = (h2)((_Float16)cwf_[c_]);                 \
        } } while (0)

#define P2_ISSUE(TP, KC, PAR) do {                                           \
        const int plane_ = ((KC) * 4 + lq) * 256;                            \
        _Pragma("unroll")                                                    \
        for (int pt_ = 0; pt_ < 2; ++pt_)                                    \
            _Pragma("unroll")                                                \
            for (int c_ = 0; c_ < 4; ++c_)                                   \
                stc[PAR][pt_][c_] = *(const uint4*)(xtb +                    \
                    (size_t)(ca2[TP][pt_][c_] + plane_) * 8);                \
        } while (0)

    P2_BILIN(0, 0);
    P2_ISSUE(0, 0, 0);

#pragma unroll
    for (int g = 0; g < 18; ++g) {
        const int tap = g >> 1, kc = g & 1, par = g & 1, tp = (g >> 1) & 1;

        // issue next group's gathers before consuming this one
        if (kc == 0) {
            P2_ISSUE(tp, 1, 1);
        } else if (tap < 8) {
            P2_ISSUE(tp ^ 1, 0, 0);     // uses bilin computed last even step
        }

        half8 bfr[4];
#pragma unroll
        for (int ot = 0; ot < 4; ++ot)
            bfr[ot] = *(const half8*)(wdf +
                ((size_t)(((tap * 2 + kc) * 4 + ot) * 64 + lane)) * 8);

        // next tap's bilin VALU runs under the in-flight loads
        if (kc == 0 && tap < 8) P2_BILIN(tap + 1, tp ^ 1);

#pragma unroll
        for (int pt = 0; pt < 2; ++pt) {
            union Uc { uint4 u; h2 p[4]; } cc0, cc1, cc2, cc3;
            cc0.u = stc[par][pt][0];
            cc1.u = stc[par][pt][1];
            cc2.u = stc[par][pt][2];
            cc3.u = stc[par][pt][3];
            union Rr { h2 s[4]; half8 v; } r;
#pragma unroll
            for (int k = 0; k < 4; ++k)
                r.s[k] = cw2[tp][pt][0] * cc0.p[k] + cw2[tp][pt][1] * cc1.p[k]
                       + cw2[tp][pt][2] * cc2.p[k] + cw2[tp][pt][3] * cc3.p[k];
#pragma unroll
            for (int ot = 0; ot < 4; ++ot)
                acc[pt][ot] = __builtin_amdgcn_mfma_f32_16x16x32_f16(
                    r.v, bfr[ot], acc[pt][ot], 0, 0, 0);
        }
    }
#undef P2_BILIN
#undef P2_ISSUE

    // ================= epilogue: float4 stores =================
#pragma unroll
    for (int ot = 0; ot < 4; ++ot) {
        const int o = ot * 16 + lm;
        const float bd = b_def[o];
#pragma unroll
        for (int pt = 0; pt < 2; ++pt) {
            const int pxs = base + pt * 16 + lq * 4;
            const floatx4 a = acc[pt][ot];
            float4 v = make_float4(a[0] + bd, a[1] + bd, a[2] + bd, a[3] + bd);
            *(float4*)&out[(((size_t)b * OUT_ + o) * H_ + y) * W_ + pxs] = v;
        }
    }
}

extern "C" void kernel_launch(void* const* d_in, const int* in_sizes, int n_in,
                              void* d_out, int out_size, void* d_ws, size_t ws_size,
                              hipStream_t stream)
{
    const float* x     = (const float*)d_in[0];
    const float* w_off = (const float*)d_in[1];
    const float* b_off = (const float*)d_in[2];
    const float* w_def = (const float*)d_in[3];
    const float* b_def = (const float*)d_in[4];
    float* out = (float*)d_out;

    _Float16* xt  = (_Float16*)d_ws;
    _Float16* wof = (_Float16*)((char*)d_ws + WOFF_OFF);
    _Float16* wdf = (_Float16*)((char*)d_ws + WDEF_OFF);

    transpose_x<<<dim3(B_ * H_), dim3(256), 0, stream>>>(
        x, xt, w_off, w_def, wof, wdf);
    deform_main<<<dim3(B_ * H_ * 2), dim3(256), 0, stream>>>(
        xt, wof, b_off, wdf, b_def, out);
}

// Round 6
// 223.500 us; speedup vs baseline: 1.3707x; 1.0060x over previous
//
#include <hip/hip_runtime.h>

// DeformConvBlock B=4,C=64,H=W=256,OUT=64 — fp16 MFMA pipeline.
// R12: fix R11's K1 OOB (tile row stride 68 indexed with px<256 -> LDS
// corruption -> absmax 8.3). K1 now: half-row (128px) per block, 2048
// blocks, tile[64][132] = 33KB LDS, float4 reads -> LDS -> granule pack ->
// 1KB-contiguous stores; all indices bounded by construction.
// deform_main is UNCHANGED from R11 (sched_barrier(0)-pinned depth-1
// pipeline + launch_bounds(256,2)) — that hypothesis finally gets measured:
// tell is VGPR 68 -> >=120 (staging live) with dur ~100us.

typedef _Float16 half8 __attribute__((ext_vector_type(8)));
typedef _Float16 h2    __attribute__((ext_vector_type(2)));
typedef float floatx4  __attribute__((ext_vector_type(4)));

namespace {
constexpr int B_ = 4, C_ = 64, H_ = 256, W_ = 256, OUT_ = 64;
constexpr int HW_ = H_ * W_;
constexpr size_t XT_BYTES = (size_t)B_ * HW_ * C_ * 2;      // 32 MB plane-major f16
constexpr size_t WOFF_OFF = XT_BYTES;                        // [9][2][2][64][8] f16
constexpr int    WOFF_N   = 9 * 2 * 2 * 64 * 8;
constexpr size_t WDEF_OFF = WOFF_OFF + (size_t)WOFF_N * 2;   // [9][2][4][64][8] f16
constexpr int    WDEF_N   = 9 * 2 * 4 * 64 * 8;
// xt granule index: (((b*256 + y)*8 + kcq)*256 + px), each granule = 8 f16 = 16B
}

// ------- K1: x CHW f32 -> plane-major f16 (+ weight prep in first 32 blocks) -
// Block = (b,y,half): 128 px. Stage 1: 8 float4 reads/thread (two 512B
// contiguous channel-row segments per wave instr) -> tile[64][132] (stride
// 132 floats: 16B-aligned, conflict-free). Stage 2: thread packs granules
// (kcq, px): 8 scalar LDS reads (consecutive px across lanes -> no
// conflicts), one 16B store; per wave instr = 1KB contiguous.
__global__ __launch_bounds__(256)
void transpose_x(const float* __restrict__ x, _Float16* __restrict__ xt,
                 const float* __restrict__ w_off, const float* __restrict__ w_def,
                 _Float16* __restrict__ wof, _Float16* __restrict__ wdf)
{
    __shared__ float tile[64 * 132];
    const int bid = blockIdx.x;            // ((b*256 + y)*2 + half)
    const int half = bid & 1;
    const int row = bid >> 1;              // b*256 + y
    const int b = row >> 8, y = row & 255;
    const int t = threadIdx.x;
    const float* __restrict__ xp = x + (size_t)b * C_ * HW_ + y * W_ + half * 128;

#pragma unroll
    for (int i = 0; i < 8; ++i) {
        const int c = i * 8 + (t >> 5);        // 0..63
        const int px = (t & 31) * 4;           // 0..124
        const float4 v = *(const float4*)&xp[(size_t)c * HW_ + px];
        *(float4*)&tile[c * 132 + px] = v;
    }
    __syncthreads();

#pragma unroll
    for (int rr = 0; rr < 4; ++rr) {
        const int kcq = (t >> 7) * 4 + rr;     // 0..7
        const int px = t & 127;                // 0..127
        union { _Float16 h[8]; uint4 u; } g;
#pragma unroll
        for (int cc = 0; cc < 8; ++cc)
            g.h[cc] = (_Float16)tile[(kcq * 8 + cc) * 132 + px];
        *(uint4*)(xt + (((size_t)row * 8 + kcq) * 256 + half * 128 + px) * 8) = g.u;
    }

    // ---- weight prep (blocks 0..31): coalesced reads, scattered stores ----
    if (bid < 32) {
        const int i0 = bid * 256 + threadIdx.x;          // 0..8191
        for (int s = i0; s < OUT_ * C_ * 9; s += 8192) {  // wdf: 36864 elems
            const int n = s / 576;                        // 576 = 64*9
            const int r = s - n * 576;
            const int c = r / 9;
            const int tap = r - c * 9;
            const int idx = ((((tap * 2 + (c >> 5)) * 4 + (n >> 4)) * 64
                              + ((c >> 3) & 3) * 16 + (n & 15)) << 3) + (c & 7);
            wdf[idx] = (_Float16)w_def[s];
        }
        for (int s = i0; s < 18 * C_ * 9; s += 8192) {    // wof: 10368 elems
            const int n = s / 576;
            const int r = s - n * 576;
            const int c = r / 9;
            const int tap = r - c * 9;
            const int idx = ((((tap * 2 + (c >> 5)) * 2 + (n >> 4)) * 64
                              + ((c >> 3) & 3) * 16 + (n & 15)) << 3) + (c & 7);
            wof[idx] = (_Float16)w_off[s];
        }
        // zero padding slots (n = 16 + (lane&15) >= 18); disjoint from above
        for (int i = i0; i < WOFF_N; i += 8192) {
            const int lane = (i >> 3) & 63, nt = (i >> 9) & 1;
            if (nt == 1 && (lane & 15) >= 2) wof[i] = (_Float16)0.0f;
        }
    }
}

// ---------------- K2 helpers ----------------
// a[i] = granule base (yc*2048 + xc); add (kc*4+lq)*256 for the channel plane.
__device__ __forceinline__ void bilin_setup(float ys, float xs, int* a, float* w)
{
    const float y0f = floorf(ys), x0f = floorf(xs);
    const float ly = ys - y0f, lx = xs - x0f;
    const int y0 = (int)y0f, x0 = (int)x0f;
    const int y1 = y0 + 1, x1 = x0 + 1;
    const int y0c = min(max(y0, 0), H_ - 1);
    const int y1c = min(max(y1, 0), H_ - 1);
    const int x0c = min(max(x0, 0), W_ - 1);
    const int x1c = min(max(x1, 0), W_ - 1);
    const float fy0 = (y0 >= 0 && y0 < H_) ? 1.0f : 0.0f;
    const float fy1 = (y1 >= 0 && y1 < H_) ? 1.0f : 0.0f;
    const float fx0 = (x0 >= 0 && x0 < W_) ? 1.0f : 0.0f;
    const float fx1 = (x1 >= 0 && x1 < W_) ? 1.0f : 0.0f;
    a[0] = y0c * 2048 + x0c;  w[0] = (1.0f - ly) * (1.0f - lx) * fy0 * fx0;
    a[1] = y0c * 2048 + x1c;  w[1] = (1.0f - ly) * lx          * fy0 * fx1;
    a[2] = y1c * 2048 + x0c;  w[2] = ly          * (1.0f - lx) * fy1 * fx0;
    a[3] = y1c * 2048 + x1c;  w[3] = ly          * lx          * fy1 * fx1;
}

// ---------------- K2: fused deform conv (f16 MFMA), pipelined ----------------
__global__ __launch_bounds__(256, 2)
void deform_main(const _Float16* __restrict__ xt,
                 const _Float16* __restrict__ wof,
                 const float* __restrict__ b_off,
                 const _Float16* __restrict__ wdf,
                 const float* __restrict__ b_def,
                 float* __restrict__ out)
{
    __shared__ float off_lds[128 * 18];       // per-pixel offsets (4 rows x 32 px)

    const int tid = threadIdx.x;
    const int lane = tid & 63;
    const int wv = tid >> 6;            // wave id: row y0+wv
    const int lm = lane & 15;
    const int lq = lane >> 4;
    const int bid = blockIdx.x;                      // 2048
    const int uid = (bid & 7) * 256 + (bid >> 3);    // XCD band swizzle
    const int colc = uid & 7;
    const int rowg = (uid >> 3) & 63;
    const int b = uid >> 9;
    const int y0 = rowg * 4;
    const int y = y0 + wv;                           // this wave's row
    const int base = colc * 32;                      // px window [base, base+32)
    const _Float16* __restrict__ xtb = xt + (size_t)b * HW_ * C_;

    // ================= phase 1: offsets via MFMA (depth-1 pipelined) ========
    {
        floatx4 acc1[2][2];
#pragma unroll
        for (int pt = 0; pt < 2; ++pt)
#pragma unroll
            for (int nt = 0; nt < 2; ++nt) acc1[pt][nt] = (floatx4)0.0f;

        uint4 st1[2][2];     // [group parity][pt]
        bool  v1[2][2];

#define P1_ISSUE(TAP, KC, PAR) do {                                          \
        const int dy_ = (TAP) / 3 - 1, dx_ = (TAP) % 3 - 1;                  \
        const int ys_ = y + dy_;                                             \
        const bool yok_ = (unsigned)ys_ < 256u;                              \
        const int ysc_ = min(max(ys_, 0), 255);                              \
        _Pragma("unroll")                                                    \
        for (int pt_ = 0; pt_ < 2; ++pt_) {                                  \
            const int pxs_ = base + pt_ * 16 + lm + dx_;                     \
            v1[PAR][pt_] = yok_ && ((unsigned)pxs_ < 256u);                  \
            const int pxc_ = min(max(pxs_, 0), 255);                         \
            st1[PAR][pt_] = *(const uint4*)(xtb +                            \
                (size_t)(ysc_ * 2048 + ((KC) * 4 + lq) * 256 + pxc_) * 8);   \
        } } while (0)

        P1_ISSUE(0, 0, 0);
        __builtin_amdgcn_sched_barrier(0);
#pragma unroll
        for (int g = 0; g < 18; ++g) {
            const int tap = g >> 1, kc = g & 1, par = g & 1;
            if (g < 17) {
                P1_ISSUE((g + 1) >> 1, (g + 1) & 1, (g + 1) & 1);
                __builtin_amdgcn_sched_barrier(0);
            }
            half8 bfr[2];
#pragma unroll
            for (int nt = 0; nt < 2; ++nt)
                bfr[nt] = *(const half8*)(wof +
                    ((size_t)(((tap * 2 + kc) * 2 + nt) * 64 + lane)) * 8);
#pragma unroll
            for (int pt = 0; pt < 2; ++pt) {
                uint4 t = st1[par][pt];
                if (!v1[par][pt]) { t.x = 0u; t.y = 0u; t.z = 0u; t.w = 0u; }
                const half8 afr = __builtin_bit_cast(half8, t);
#pragma unroll
                for (int nt = 0; nt < 2; ++nt)
                    acc1[pt][nt] = __builtin_amdgcn_mfma_f32_16x16x32_f16(
                        afr, bfr[nt], acc1[pt][nt], 0, 0, 0);
            }
        }
#undef P1_ISSUE

#pragma unroll
        for (int nt = 0; nt < 2; ++nt) {
            const int j = nt * 16 + lm;
            if (j < 18) {
                const float bj = b_off[j];
#pragma unroll
                for (int pt = 0; pt < 2; ++pt) {
#pragma unroll
                    for (int r = 0; r < 4; ++r) {
                        const int lpx = wv * 32 + pt * 16 + lq * 4 + r;
                        off_lds[lpx * 18 + j] = acc1[pt][nt][r] + bj;
                    }
                }
            }
        }
    }
    __syncthreads();   // the ONLY barrier

    // ================= phase 2: pipelined gather + MFMA =====================
    floatx4 acc[2][4];
#pragma unroll
    for (int pt = 0; pt < 2; ++pt)
#pragma unroll
        for (int ot = 0; ot < 4; ++ot) acc[pt][ot] = (floatx4)0.0f;

    int   ca2[2][2][4];   // [tap parity][pt][corner] granule bases
    h2    cw2[2][2][4];   // [tap parity][pt][corner] f16 blend weights
    uint4 stc[2][2][4];   // [group parity][pt][corner] staged corner data

#define P2_BILIN(TAP, TP) do {                                               \
        const int ki_ = (TAP) / 3, kj_ = (TAP) % 3;                          \
        _Pragma("unroll")                                                    \
        for (int pt_ = 0; pt_ < 2; ++pt_) {                                  \
            const int lpx_ = wv * 32 + pt_ * 16 + lm;                        \
            const float2 o2_ = *(const float2*)&off_lds[lpx_ * 18 + (TAP) * 2]; \
            const float ys_ = (float)(y + ki_ - 1) + o2_.x;                  \
            const float xs_ = (float)(base + pt_ * 16 + lm + kj_ - 1) + o2_.y; \
            float cwf_[4];                                                   \
            bilin_setup(ys_, xs_, ca2[TP][pt_], cwf_);                       \
            _Pragma("unroll")                                                \
            for (int c_ = 0; c_ < 4; ++c_)                                   \
                cw2[TP][pt_][c_] = (h2)((_Float16)cwf_[c_]);                 \
        } } while (0)

#define P2_ISSUE(TP, KC, PAR) do {                                           \
        const int plane_ = ((KC) * 4 + lq) * 256;                            \
        _Pragma("unroll")                                                    \
        for (int pt_ = 0; pt_ < 2; ++pt_)                                    \
            _Pragma("unroll")                                                \
            for (int c_ = 0; c_ < 4; ++c_)                                   \
                stc[PAR][pt_][c_] = *(const uint4*)(xtb +                    \
                    (size_t)(ca2[TP][pt_][c_] + plane_) * 8);                \
        } while (0)

    P2_BILIN(0, 0);
    P2_ISSUE(0, 0, 0);
    __builtin_amdgcn_sched_barrier(0);

#pragma unroll
    for (int g = 0; g < 18; ++g) {
        const int tap = g >> 1, kc = g & 1, par = g & 1, tp = (g >> 1) & 1;

        // issue next group's gathers before consuming this one; pin them high
        if (kc == 0) {
            P2_ISSUE(tp, 1, 1);
            __builtin_amdgcn_sched_barrier(0);
        } else if (tap < 8) {
            P2_ISSUE(tp ^ 1, 0, 0);     // uses bilin computed last even step
            __builtin_amdgcn_sched_barrier(0);
        }

        half8 bfr[4];
#pragma unroll
        for (int ot = 0; ot < 4; ++ot)
            bfr[ot] = *(const half8*)(wdf +
                ((size_t)(((tap * 2 + kc) * 4 + ot) * 64 + lane)) * 8);

        // next tap's bilin VALU runs under the in-flight loads
        if (kc == 0 && tap < 8) P2_BILIN(tap + 1, tp ^ 1);

#pragma unroll
        for (int pt = 0; pt < 2; ++pt) {
            union Uc { uint4 u; h2 p[4]; } cc0, cc1, cc2, cc3;
            cc0.u = stc[par][pt][0];
            cc1.u = stc[par][pt][1];
            cc2.u = stc[par][pt][2];
            cc3.u = stc[par][pt][3];
            union Rr { h2 s[4]; half8 v; } r;
#pragma unroll
            for (int k = 0; k < 4; ++k)
                r.s[k] = cw2[tp][pt][0] * cc0.p[k] + cw2[tp][pt][1] * cc1.p[k]
                       + cw2[tp][pt][2] * cc2.p[k] + cw2[tp][pt][3] * cc3.p[k];
#pragma unroll
            for (int ot = 0; ot < 4; ++ot)
                acc[pt][ot] = __builtin_amdgcn_mfma_f32_16x16x32_f16(
                    r.v, bfr[ot], acc[pt][ot], 0, 0, 0);
        }
    }
#undef P2_BILIN
#undef P2_ISSUE

    // ================= epilogue: float4 stores =================
#pragma unroll
    for (int ot = 0; ot < 4; ++ot) {
        const int o = ot * 16 + lm;
        const float bd = b_def[o];
#pragma unroll
        for (int pt = 0; pt < 2; ++pt) {
            const int pxs = base + pt * 16 + lq * 4;
            const floatx4 a = acc[pt][ot];
            float4 v = make_float4(a[0] + bd, a[1] + bd, a[2] + bd, a[3] + bd);
            *(float4*)&out[(((size_t)b * OUT_ + o) * H_ + y) * W_ + pxs] = v;
        }
    }
}

extern "C" void kernel_launch(void* const* d_in, const int* in_sizes, int n_in,
                              void* d_out, int out_size, void* d_ws, size_t ws_size,
                              hipStream_t stream)
{
    const float* x     = (const float*)d_in[0];
    const float* w_off = (const float*)d_in[1];
    const float* b_off = (const float*)d_in[2];
    const float* w_def = (const float*)d_in[3];
    const float* b_def = (const float*)d_in[4];
    float* out = (float*)d_out;

    _Float16* xt  = (_Float16*)d_ws;
    _Float16* wof = (_Float16*)((char*)d_ws + WOFF_OFF);
    _Float16* wdf = (_Float16*)((char*)d_ws + WDEF_OFF);

    transpose_x<<<dim3(B_ * H_ * 2), dim3(256), 0, stream>>>(
        x, xt, w_off, w_def, wof, wdf);
    deform_main<<<dim3(B_ * H_ * 2), dim3(256), 0, stream>>>(
        xt, wof, b_off, wdf, b_def, out);
}